// Round 16
// baseline (534.575 us; speedup 1.0000x reference)
//
#include <hip/hip_runtime.h>
#include <hip/hip_bf16.h>
#include <math.h>

#define TT 8192
#define DDIM 1024
#define EE 8
#define FF 4096
#define CCAP 2048
#define NSLOT 16384

typedef __attribute__((ext_vector_type(4))) float f32x4;
typedef __attribute__((ext_vector_type(16))) float f32x16;
typedef __attribute__((ext_vector_type(8))) short bf16x8;

typedef const __attribute__((address_space(1))) void CGV;
typedef __attribute__((address_space(3))) void LDSV;

__device__ __forceinline__ short f2bf(float f) {
  unsigned u = __builtin_bit_cast(unsigned, f);
  u += 0x7fffu + ((u >> 16) & 1u);
  return (short)(u >> 16);
}
__device__ __forceinline__ float bf2f(short s) {
  unsigned u = ((unsigned)(unsigned short)s) << 16;
  return __builtin_bit_cast(float, u);
}

// ---------------- gating: logits, top-2, normalized gates (f32) ----------------
__global__ void __launch_bounds__(256) gate_kernel(const float* __restrict__ x,
    const float* __restrict__ wg, int* __restrict__ idx1, int* __restrict__ idx2,
    float* __restrict__ g1s, float* __restrict__ g2s) {
  int lane = threadIdx.x & 63;
  int t = blockIdx.x * 4 + (threadIdx.x >> 6);
  const float* xr = x + (size_t)t * DDIM;
  float acc[8];
#pragma unroll
  for (int e = 0; e < 8; ++e) acc[e] = 0.f;
#pragma unroll
  for (int i = 0; i < 4; ++i) {
    int d = lane * 4 + i * 256;
    f32x4 xv = *(const f32x4*)(xr + d);
#pragma unroll
    for (int j = 0; j < 4; ++j) {
      const f32x4* wr = (const f32x4*)(wg + (size_t)(d + j) * 8);
      f32x4 w0 = wr[0], w1 = wr[1];
#pragma unroll
      for (int e = 0; e < 4; ++e) { acc[e] += xv[j] * w0[e]; acc[e + 4] += xv[j] * w1[e]; }
    }
  }
#pragma unroll
  for (int e = 0; e < 8; ++e) {
#pragma unroll
    for (int o = 32; o > 0; o >>= 1) acc[e] += __shfl_xor(acc[e], o, 64);
  }
  if (lane == 0) {
    int i1 = 0; float l1 = acc[0];
#pragma unroll
    for (int e = 1; e < 8; ++e) if (acc[e] > l1) { l1 = acc[e]; i1 = e; }
    int i2 = -1; float l2 = -3.0e38f;
#pragma unroll
    for (int e = 0; e < 8; ++e) if (e != i1 && acc[e] > l2) { l2 = acc[e]; i2 = e; }
    float e2 = expf(l2 - l1);           // <= 1, stable
    float inv = 1.f / (1.f + e2);
    idx1[t] = i1; idx2[t] = i2;
    g1s[t] = inv; g2s[t] = e2 * inv;    // == g1/(g1+g2), g2/(g1+g2)
  }
}

// ---------------- order-preserving slot assignment (GShard cumsum) ----------------
__global__ void __launch_bounds__(1024) scan_kernel(const int* __restrict__ idx1,
    const int* __restrict__ idx2, const float* __restrict__ g1s, const float* __restrict__ g2s,
    int* __restrict__ f1, int* __restrict__ f2, float* __restrict__ gg1, float* __restrict__ gg2,
    int* __restrict__ slot_token) {
  __shared__ unsigned long long slo[1024], shi[1024];
  int tid = threadIdx.x;
  for (int i = tid; i < NSLOT; i += 1024) slot_token[i] = -1;
  int t0 = tid * 8;
  int e1[8], e2[8];
#pragma unroll
  for (int i = 0; i < 8; ++i) { e1[i] = idx1[t0 + i]; e2[i] = idx2[t0 + i]; }

  unsigned long long lo = 0, hi = 0;
#pragma unroll
  for (int i = 0; i < 8; ++i) {
    int e = e1[i];
    if (e < 4) lo += 1ull << (16 * e); else hi += 1ull << (16 * (e - 4));
  }
  slo[tid] = lo; shi[tid] = hi; __syncthreads();
  for (int off = 1; off < 1024; off <<= 1) {
    unsigned long long alo = 0, ahi = 0;
    if (tid >= off) { alo = slo[tid - off]; ahi = shi[tid - off]; }
    __syncthreads();
    slo[tid] += alo; shi[tid] += ahi;
    __syncthreads();
  }
  unsigned long long exlo = slo[tid] - lo, exhi = shi[tid] - hi;
  unsigned long long tlo = slo[1023], thi = shi[1023];
  __syncthreads();
  int base1[8], tot1[8];
#pragma unroll
  for (int e = 0; e < 4; ++e) {
    base1[e]     = (int)((exlo >> (16 * e)) & 0xFFFF);
    base1[e + 4] = (int)((exhi >> (16 * e)) & 0xFFFF);
    tot1[e]      = (int)((tlo  >> (16 * e)) & 0xFFFF);
    tot1[e + 4]  = (int)((thi  >> (16 * e)) & 0xFFFF);
  }

  lo = 0; hi = 0;
#pragma unroll
  for (int i = 0; i < 8; ++i) {
    int e = e2[i];
    if (e < 4) lo += 1ull << (16 * e); else hi += 1ull << (16 * (e - 4));
  }
  slo[tid] = lo; shi[tid] = hi; __syncthreads();
  for (int off = 1; off < 1024; off <<= 1) {
    unsigned long long alo = 0, ahi = 0;
    if (tid >= off) { alo = slo[tid - off]; ahi = shi[tid - off]; }
    __syncthreads();
    slo[tid] += alo; shi[tid] += ahi;
    __syncthreads();
  }
  exlo = slo[tid] - lo; exhi = shi[tid] - hi;
  int base2[8];
#pragma unroll
  for (int e = 0; e < 4; ++e) {
    base2[e]     = (int)((exlo >> (16 * e)) & 0xFFFF);
    base2[e + 4] = (int)((exhi >> (16 * e)) & 0xFFFF);
  }

#pragma unroll
  for (int i = 0; i < 8; ++i) {
    int t = t0 + i;
    int a = e1[i];
    int p1 = base1[a]++;
    int k1 = (p1 < CCAP);
    int s1 = a * CCAP + (k1 ? p1 : CCAP - 1);
    f1[t] = s1;
    gg1[t] = k1 ? g1s[t] : 0.f;
    if (k1) slot_token[s1] = t;

    int b = e2[i];
    int p2 = base2[b] + tot1[b];
    base2[b]++;
    int k2 = (p2 < CCAP);
    int s2 = b * CCAP + (k2 ? p2 : CCAP - 1);
    f2[t] = s2;
    gg2[t] = k2 ? g2s[t] : 0.f;
    if (k2) slot_token[s2] = t;
  }
}

// ---------------- dispatch: gather token rows into slot rows (bf16) ----------------
__global__ void __launch_bounds__(128) dispatch_kernel(const float* __restrict__ x,
    const int* __restrict__ slot_token, short* __restrict__ disp) {
  int slot = blockIdx.x;
  int tid = threadIdx.x;
  int tok = slot_token[slot];
  short* dst = disp + (size_t)slot * DDIM + tid * 8;
  bf16x8 v;
  if (tok >= 0) {
    const float* src = x + (size_t)tok * DDIM + tid * 8;
    f32x4 a = *(const f32x4*)src;
    f32x4 b = *(const f32x4*)(src + 4);
#pragma unroll
    for (int j = 0; j < 4; ++j) { v[j] = f2bf(a[j]); v[j + 4] = f2bf(b[j]); }
  } else {
#pragma unroll
    for (int j = 0; j < 8; ++j) v[j] = 0;
  }
  *(bf16x8*)dst = v;
}

// ---------------- weight transpose + f32->bf16:  [E][R][Cc] -> [E][Cc][R] ----------------
__global__ void __launch_bounds__(256) tconv_kernel(const float* __restrict__ in,
    short* __restrict__ outp, int R, int Cc) {
  __shared__ float tl[32][33];
  long e = blockIdx.z;
  const float* src = in + e * (long)R * Cc;
  short* dst = outp + e * (long)R * Cc;
  int x0 = blockIdx.x * 32, y0 = blockIdx.y * 32;
  int tx = threadIdx.x, ty = threadIdx.y;
#pragma unroll
  for (int r = 0; r < 4; ++r)
    tl[ty * 4 + r][tx] = src[(long)(y0 + ty * 4 + r) * Cc + x0 + tx];
  __syncthreads();
#pragma unroll
  for (int r = 0; r < 4; ++r)
    dst[(long)(x0 + ty * 4 + r) * R + y0 + tx] = f2bf(tl[tx][ty * 4 + r]);
}

// ===== bf16 GEMM, 128x128 tile, BK=32, dbuf LDS (32KB), 4 waves, 32x32x16 MFMA =====
// R8/R15 structure (best: 230us/GEMM) with ONE lever changed: 16x16x32 MFMA ->
// 32x32x16. Per K32-step/wave: 8 MFMA instead of 16 (fewer issue slots vs 44%
// VALUBusy) and the 32x32 pipe is ~13% faster per FLOP (m119: 2495 vs 2176 TF).
// LDS traffic identical (4+4 x 16B frags/lane/step). Bank check: rows=l&31,
// chunk=ksub*2+(l>>5); quad(r)=(r&1)*4+(chunk^((r>>1)&3)) bijective per 8-row
// group per kh-half -> 8 accesses/quad = b128 minimum (conflict-free, same
// swizzle slot=kc^((row>>1)&3)). Registers: acc 2x2x16=64 f32 (same), frags 32
// (same) -> (256,4) spill-free. Layouts (guide-verified m74/m101): A/B in:
// row=lane&31, k=(lane>>5)*8+elem; C/D out: col=lane&31,
// row=(reg&3)+8*(reg>>2)+4*(lane>>5). T1 XCD swizzle kept (grid%8==0).
template<int KD, int LDA, int LDB, int LDC, bool GELU>
__global__ void __launch_bounds__(256, 4) gemm128(const short* __restrict__ Ag,
    const short* __restrict__ Bg, short* __restrict__ Cg,
    long aes, long bes, long ces, int nbx, int nby) {
  constexpr int KT = KD / 32;              // K-tiles of 32
  __shared__ alignas(16) short ldsA[2][128 * 32];
  __shared__ alignas(16) short ldsB[2][128 * 32];

  int bid = blockIdx.x;
  int wid = (bid & 7) * ((int)gridDim.x >> 3) + (bid >> 3);   // T1 (grid%8==0)
  int bx = wid % nbx;
  int rem = wid / nbx;
  int by = rem % nby;
  int e  = rem / nby;

  const short* A = Ag + (long)e * aes + (long)by * 128 * LDA;
  const short* B = Bg + (long)e * bes + (long)bx * 128 * LDB;
  short* Cp = Cg + (long)e * ces + (long)by * 128 * LDC + bx * 128;

  int tid = threadIdx.x;
  int l = tid & 63;
  int w = tid >> 6;
  int wm = w >> 1, wn = w & 1;             // 2 x 2 wave grid, 64x64 out per wave

  f32x16 acc[2][2];
#pragma unroll
  for (int m = 0; m < 2; ++m)
#pragma unroll
    for (int n = 0; n < 2; ++n)
#pragma unroll
      for (int r = 0; r < 16; ++r) acc[m][n][r] = 0.f;

  // stage one 128x32 K-tile of A and B (2 granules of 16B each per thread).
  // LDS dest linear (granule g = row*4+slot); global source slot pre-swizzled.
  auto STAGE = [&](int buf, int kt) {
#pragma unroll
    for (int c = 0; c < 2; ++c) {
      int g = c * 256 + tid;               // 0..511
      int row = g >> 2, sl = g & 3;
      int col = kt * 32 + ((sl ^ ((row >> 1) & 3)) << 3);
      __builtin_amdgcn_global_load_lds((CGV*)(A + (long)row * LDA + col),
                                       (LDSV*)(&ldsA[buf][g * 8]), 16, 0, 0);
      __builtin_amdgcn_global_load_lds((CGV*)(B + (long)row * LDB + col),
                                       (LDSV*)(&ldsB[buf][g * 8]), 16, 0, 0);
    }
  };

  int l31 = l & 31;
  int kh = l >> 5;                         // 0/1: k-half within each K=16 MFMA

  STAGE(0, 0);
  __syncthreads();

  for (int t = 0; t < KT; ++t) {
    int cur = t & 1;
    if (t + 1 < KT) STAGE(cur ^ 1, t + 1);

    bf16x8 a[2][2], b[2][2];               // [m or n tile][ksub]
#pragma unroll
    for (int mm = 0; mm < 2; ++mm) {
      int row = wm * 64 + mm * 32 + l31;
      const char* rp = (const char*)&ldsA[cur][row * 32];
      int swz = (row >> 1) & 3;
#pragma unroll
      for (int ks = 0; ks < 2; ++ks) {
        int kc = ks * 2 + kh;              // 16B chunk index 0..3
        a[mm][ks] = *(const bf16x8*)(rp + ((kc ^ swz) << 4));
      }
    }
#pragma unroll
    for (int nn = 0; nn < 2; ++nn) {
      int row = wn * 64 + nn * 32 + l31;
      const char* rp = (const char*)&ldsB[cur][row * 32];
      int swz = (row >> 1) & 3;
#pragma unroll
      for (int ks = 0; ks < 2; ++ks) {
        int kc = ks * 2 + kh;
        b[nn][ks] = *(const bf16x8*)(rp + ((kc ^ swz) << 4));
      }
    }

#pragma unroll
    for (int ks = 0; ks < 2; ++ks)
#pragma unroll
      for (int mm = 0; mm < 2; ++mm)
#pragma unroll
        for (int nn = 0; nn < 2; ++nn)
          acc[mm][nn] = __builtin_amdgcn_mfma_f32_32x32x16_bf16(
              a[mm][ks], b[nn][ks], acc[mm][nn], 0, 0, 0);

    if (t + 1 < KT) __syncthreads();
  }

  // epilogue: col=lane&31, row=(reg&3)+8*(reg>>2)+4*(lane>>5) (verified m74/m101)
#pragma unroll
  for (int mm = 0; mm < 2; ++mm) {
    int rbase = wm * 64 + mm * 32 + 4 * kh;
#pragma unroll
    for (int nn = 0; nn < 2; ++nn) {
      int col = wn * 64 + nn * 32 + l31;
#pragma unroll
      for (int r = 0; r < 16; ++r) {
        int row = rbase + (r & 3) + 8 * (r >> 2);
        float vv = acc[mm][nn][r];
        if (GELU) vv = 0.5f * vv * (1.f + erff(vv * 0.70710678118654752f));
        Cp[(long)row * LDC + col] = f2bf(vv);
      }
    }
  }
}

// ---------------- combine: out[t] = gg1*eo[f1] + gg2*eo[f2] (f32 out) ----------------
__global__ void __launch_bounds__(128) combine_kernel(const short* __restrict__ eo,
    const int* __restrict__ f1, const int* __restrict__ f2,
    const float* __restrict__ gg1, const float* __restrict__ gg2, float* __restrict__ out) {
  int t = blockIdx.x, tid = threadIdx.x;
  float a = gg1[t], b = gg2[t];
  long s1 = f1[t], s2 = f2[t];
  bf16x8 v1 = *(const bf16x8*)(eo + s1 * DDIM + tid * 8);
  bf16x8 v2 = *(const bf16x8*)(eo + s2 * DDIM + tid * 8);
  f32x4 o0, o1;
#pragma unroll
  for (int j = 0; j < 4; ++j) {
    o0[j] = a * bf2f(v1[j])     + b * bf2f(v2[j]);
    o1[j] = a * bf2f(v1[j + 4]) + b * bf2f(v2[j + 4]);
  }
  float* dst = out + (size_t)t * DDIM + tid * 8;
  *(f32x4*)dst = o0;
  *(f32x4*)(dst + 4) = o1;
}

extern "C" void kernel_launch(void* const* d_in, const int* in_sizes, int n_in,
                              void* d_out, int out_size, void* d_ws, size_t ws_size,
                              hipStream_t stream) {
  const float* x      = (const float*)d_in[0];
  const float* wg     = (const float*)d_in[1];
  const float* w_gate = (const float*)d_in[2];
  const float* w_down = (const float*)d_in[3];
  float* out = (float*)d_out;

  char* ws = (char*)d_ws;
  size_t off = 0;
  auto alloc = [&](size_t bytes) -> void* {
    void* p = ws + off;
    off += (bytes + 255) & ~(size_t)255;
    return p;
  };
  short* wbg  = (short*)alloc((size_t)EE * FF * DDIM * 2);   // [E][F][D] bf16
  short* wbd  = (short*)alloc((size_t)EE * DDIM * FF * 2);   // [E][D][F] bf16
  short* disp = (short*)alloc((size_t)NSLOT * DDIM * 2);
  short* eo   = (short*)alloc((size_t)NSLOT * DDIM * 2);
  int*   idx1 = (int*)alloc(TT * 4);
  int*   idx2 = (int*)alloc(TT * 4);
  int*   f1   = (int*)alloc(TT * 4);
  int*   f2   = (int*)alloc(TT * 4);
  float* g1s  = (float*)alloc(TT * 4);
  float* g2s  = (float*)alloc(TT * 4);
  float* gg1  = (float*)alloc(TT * 4);
  float* gg2  = (float*)alloc(TT * 4);
  int*   slot_token = (int*)alloc(NSLOT * 4);
  size_t h_full = (size_t)NSLOT * FF * 2;
  bool full = (off + h_full) <= ws_size;
  short* h = (short*)(ws + off);

  // weights -> bf16, transposed to [N][K]
  tconv_kernel<<<dim3(FF / 32, DDIM / 32, EE), dim3(32, 8), 0, stream>>>(w_gate, wbg, DDIM, FF);
  tconv_kernel<<<dim3(DDIM / 32, FF / 32, EE), dim3(32, 8), 0, stream>>>(w_down, wbd, FF, DDIM);

  gate_kernel<<<TT / 4, 256, 0, stream>>>(x, wg, idx1, idx2, g1s, g2s);
  scan_kernel<<<1, 1024, 0, stream>>>(idx1, idx2, g1s, g2s, f1, f2, gg1, gg2, slot_token);
  dispatch_kernel<<<NSLOT, 128, 0, stream>>>(x, slot_token, disp);

  if (full) {
    gemm128<DDIM, DDIM, DDIM, FF, true><<<(FF / 128) * (CCAP / 128) * EE, 256, 0, stream>>>(
        disp, wbg, h, (long)CCAP * DDIM, (long)FF * DDIM, (long)CCAP * FF, FF / 128, CCAP / 128);
    gemm128<FF, FF, FF, DDIM, false><<<(DDIM / 128) * (CCAP / 128) * EE, 256, 0, stream>>>(
        h, wbd, eo, (long)CCAP * FF, (long)DDIM * FF, (long)CCAP * DDIM, DDIM / 128, CCAP / 128);
  } else {
    for (int e = 0; e < EE; ++e) {
      gemm128<DDIM, DDIM, DDIM, FF, true><<<(FF / 128) * (CCAP / 128), 256, 0, stream>>>(
          disp + (long)e * CCAP * DDIM, wbg + (long)e * FF * DDIM, h, 0, 0, 0, FF / 128, CCAP / 128);
      gemm128<FF, FF, FF, DDIM, false><<<(DDIM / 128) * (CCAP / 128), 256, 0, stream>>>(
          h, wbd + (long)e * DDIM * FF, eo + (long)e * CCAP * DDIM, 0, 0, 0, DDIM / 128, CCAP / 128);
    }
  }

  combine_kernel<<<TT, 128, 0, stream>>>(eo, f1, f2, gg1, gg2, out);
}

// Round 17
// 506.861 us; speedup vs baseline: 1.0547x; 1.0547x over previous
//
#include <hip/hip_runtime.h>
#include <hip/hip_bf16.h>
#include <math.h>

#define TT 8192
#define DDIM 1024
#define EE 8
#define FF 4096
#define CCAP 2048
#define NSLOT 16384

typedef __attribute__((ext_vector_type(4))) float f32x4;
typedef __attribute__((ext_vector_type(8))) short bf16x8;

typedef const __attribute__((address_space(1))) void CGV;
typedef __attribute__((address_space(3))) void LDSV;

__device__ __forceinline__ short f2bf(float f) {
  unsigned u = __builtin_bit_cast(unsigned, f);
  u += 0x7fffu + ((u >> 16) & 1u);
  return (short)(u >> 16);
}
__device__ __forceinline__ float bf2f(short s) {
  unsigned u = ((unsigned)(unsigned short)s) << 16;
  return __builtin_bit_cast(float, u);
}

// ---------------- gating: logits, top-2, normalized gates (f32) ----------------
__global__ void __launch_bounds__(256) gate_kernel(const float* __restrict__ x,
    const float* __restrict__ wg, int* __restrict__ idx1, int* __restrict__ idx2,
    float* __restrict__ g1s, float* __restrict__ g2s) {
  int lane = threadIdx.x & 63;
  int t = blockIdx.x * 4 + (threadIdx.x >> 6);
  const float* xr = x + (size_t)t * DDIM;
  float acc[8];
#pragma unroll
  for (int e = 0; e < 8; ++e) acc[e] = 0.f;
#pragma unroll
  for (int i = 0; i < 4; ++i) {
    int d = lane * 4 + i * 256;
    f32x4 xv = *(const f32x4*)(xr + d);
#pragma unroll
    for (int j = 0; j < 4; ++j) {
      const f32x4* wr = (const f32x4*)(wg + (size_t)(d + j) * 8);
      f32x4 w0 = wr[0], w1 = wr[1];
#pragma unroll
      for (int e = 0; e < 4; ++e) { acc[e] += xv[j] * w0[e]; acc[e + 4] += xv[j] * w1[e]; }
    }
  }
#pragma unroll
  for (int e = 0; e < 8; ++e) {
#pragma unroll
    for (int o = 32; o > 0; o >>= 1) acc[e] += __shfl_xor(acc[e], o, 64);
  }
  if (lane == 0) {
    int i1 = 0; float l1 = acc[0];
#pragma unroll
    for (int e = 1; e < 8; ++e) if (acc[e] > l1) { l1 = acc[e]; i1 = e; }
    int i2 = -1; float l2 = -3.0e38f;
#pragma unroll
    for (int e = 0; e < 8; ++e) if (e != i1 && acc[e] > l2) { l2 = acc[e]; i2 = e; }
    float e2 = expf(l2 - l1);           // <= 1, stable
    float inv = 1.f / (1.f + e2);
    idx1[t] = i1; idx2[t] = i2;
    g1s[t] = inv; g2s[t] = e2 * inv;    // == g1/(g1+g2), g2/(g1+g2)
  }
}

// ---------------- order-preserving slot assignment (GShard cumsum) ----------------
__global__ void __launch_bounds__(1024) scan_kernel(const int* __restrict__ idx1,
    const int* __restrict__ idx2, const float* __restrict__ g1s, const float* __restrict__ g2s,
    int* __restrict__ f1, int* __restrict__ f2, float* __restrict__ gg1, float* __restrict__ gg2,
    int* __restrict__ slot_token) {
  __shared__ unsigned long long slo[1024], shi[1024];
  int tid = threadIdx.x;
  for (int i = tid; i < NSLOT; i += 1024) slot_token[i] = -1;
  int t0 = tid * 8;
  int e1[8], e2[8];
#pragma unroll
  for (int i = 0; i < 8; ++i) { e1[i] = idx1[t0 + i]; e2[i] = idx2[t0 + i]; }

  unsigned long long lo = 0, hi = 0;
#pragma unroll
  for (int i = 0; i < 8; ++i) {
    int e = e1[i];
    if (e < 4) lo += 1ull << (16 * e); else hi += 1ull << (16 * (e - 4));
  }
  slo[tid] = lo; shi[tid] = hi; __syncthreads();
  for (int off = 1; off < 1024; off <<= 1) {
    unsigned long long alo = 0, ahi = 0;
    if (tid >= off) { alo = slo[tid - off]; ahi = shi[tid - off]; }
    __syncthreads();
    slo[tid] += alo; shi[tid] += ahi;
    __syncthreads();
  }
  unsigned long long exlo = slo[tid] - lo, exhi = shi[tid] - hi;
  unsigned long long tlo = slo[1023], thi = shi[1023];
  __syncthreads();
  int base1[8], tot1[8];
#pragma unroll
  for (int e = 0; e < 4; ++e) {
    base1[e]     = (int)((exlo >> (16 * e)) & 0xFFFF);
    base1[e + 4] = (int)((exhi >> (16 * e)) & 0xFFFF);
    tot1[e]      = (int)((tlo  >> (16 * e)) & 0xFFFF);
    tot1[e + 4]  = (int)((thi  >> (16 * e)) & 0xFFFF);
  }

  lo = 0; hi = 0;
#pragma unroll
  for (int i = 0; i < 8; ++i) {
    int e = e2[i];
    if (e < 4) lo += 1ull << (16 * e); else hi += 1ull << (16 * (e - 4));
  }
  slo[tid] = lo; shi[tid] = hi; __syncthreads();
  for (int off = 1; off < 1024; off <<= 1) {
    unsigned long long alo = 0, ahi = 0;
    if (tid >= off) { alo = slo[tid - off]; ahi = shi[tid - off]; }
    __syncthreads();
    slo[tid] += alo; shi[tid] += ahi;
    __syncthreads();
  }
  exlo = slo[tid] - lo; exhi = shi[tid] - hi;
  int base2[8];
#pragma unroll
  for (int e = 0; e < 4; ++e) {
    base2[e]     = (int)((exlo >> (16 * e)) & 0xFFFF);
    base2[e + 4] = (int)((exhi >> (16 * e)) & 0xFFFF);
  }

#pragma unroll
  for (int i = 0; i < 8; ++i) {
    int t = t0 + i;
    int a = e1[i];
    int p1 = base1[a]++;
    int k1 = (p1 < CCAP);
    int s1 = a * CCAP + (k1 ? p1 : CCAP - 1);
    f1[t] = s1;
    gg1[t] = k1 ? g1s[t] : 0.f;
    if (k1) slot_token[s1] = t;

    int b = e2[i];
    int p2 = base2[b] + tot1[b];
    base2[b]++;
    int k2 = (p2 < CCAP);
    int s2 = b * CCAP + (k2 ? p2 : CCAP - 1);
    f2[t] = s2;
    gg2[t] = k2 ? g2s[t] : 0.f;
    if (k2) slot_token[s2] = t;
  }
}

// ---------------- dispatch: gather token rows into slot rows (bf16) ----------------
__global__ void __launch_bounds__(128) dispatch_kernel(const float* __restrict__ x,
    const int* __restrict__ slot_token, short* __restrict__ disp) {
  int slot = blockIdx.x;
  int tid = threadIdx.x;
  int tok = slot_token[slot];
  short* dst = disp + (size_t)slot * DDIM + tid * 8;
  bf16x8 v;
  if (tok >= 0) {
    const float* src = x + (size_t)tok * DDIM + tid * 8;
    f32x4 a = *(const f32x4*)src;
    f32x4 b = *(const f32x4*)(src + 4);
#pragma unroll
    for (int j = 0; j < 4; ++j) { v[j] = f2bf(a[j]); v[j + 4] = f2bf(b[j]); }
  } else {
#pragma unroll
    for (int j = 0; j < 8; ++j) v[j] = 0;
  }
  *(bf16x8*)dst = v;
}

// ---- weight transpose + f32->bf16: [E][R][Cc] -> [E][Cc][R], 16B stores ----
// 64(R) x 32(Cc) tile, 256 thr. Load: thread (c=tid&31, rb=tid>>5) reads 8 rows
// scalar-coalesced (32 lanes x 4B = 128B lines). LDS [64][33] f32: write bank
// (r+c)%32 -> 2 lanes/bank (free); read tl[rr0+j][cc] bank (rr0+j+cc)%32 ->
// 2 lanes/bank (free). Store: thread (cc=tid>>3, rr0=(tid&7)*8) packs 8 bf16 ->
// one 16B store; 8 threads = 128B contiguous line per output row (vs 2B scalar
// half-line stores before, G13 fix).
__global__ void __launch_bounds__(256) tconv_kernel(const float* __restrict__ in,
    short* __restrict__ outp, int R, int Cc) {
  __shared__ float tl[64][33];
  long e = blockIdx.z;
  const float* src = in + e * (long)R * Cc;
  short* dst = outp + e * (long)R * Cc;
  int y0 = blockIdx.y * 64;                // R-tile base
  int x0 = blockIdx.x * 32;                // Cc-tile base
  int tid = threadIdx.x;
  int c = tid & 31, rb = tid >> 5;         // load role
#pragma unroll
  for (int j = 0; j < 8; ++j) {
    int r = rb * 8 + j;
    tl[r][c] = src[(long)(y0 + r) * Cc + x0 + c];
  }
  __syncthreads();
  int cc = tid >> 3, rr0 = (tid & 7) * 8;  // store role
  bf16x8 v;
#pragma unroll
  for (int j = 0; j < 8; ++j) v[j] = f2bf(tl[rr0 + j][cc]);
  *(bf16x8*)(dst + (long)(x0 + cc) * R + y0 + rr0) = v;
}

// ===== bf16 GEMM, 128x128 tile, BK=32, dbuf LDS (32KB), 4 waves of 64x64 =====
// FINAL (R8/R15 configuration — best measured: 230us/GEMM, 510us total).
// Session map: 64x64 wave tiles minimize LDS traffic; unified VGPR+AGPR live set
// (~120 regs) caps residency at 4 blocks/CU ((256,5/6/8) -> spills, R13/R14).
// Scheduling machinery regressed 5/5 (R2-R4, R9, R10); 32x32x16 MFMA regressed
// (R16: 4-way read conflicts + scattered 2B C-stores); A-direct regressed (R12).
// Cross-block overlap via the per-tile __syncthreads is the working mechanism.
// Bank swizzle: 64-B rows alternate base bank 0/16; slot=kq^((row>>1)&3) makes
// bank-quads bijective over 8 rows -> 2 lanes/bank (free). Conflicts=0 verified.
// T1 bijective XCD swizzle (grid%8==0).
template<int KD, int LDA, int LDB, int LDC, bool GELU>
__global__ void __launch_bounds__(256, 4) gemm128(const short* __restrict__ Ag,
    const short* __restrict__ Bg, short* __restrict__ Cg,
    long aes, long bes, long ces, int nbx, int nby) {
  constexpr int KT = KD / 32;              // K-tiles of 32
  __shared__ alignas(16) short ldsA[2][128 * 32];
  __shared__ alignas(16) short ldsB[2][128 * 32];

  int bid = blockIdx.x;
  int wid = (bid & 7) * ((int)gridDim.x >> 3) + (bid >> 3);   // T1 (grid%8==0)
  int bx = wid % nbx;
  int rem = wid / nbx;
  int by = rem % nby;
  int e  = rem / nby;

  const short* A = Ag + (long)e * aes + (long)by * 128 * LDA;
  const short* B = Bg + (long)e * bes + (long)bx * 128 * LDB;
  short* Cp = Cg + (long)e * ces + (long)by * 128 * LDC + bx * 128;

  int tid = threadIdx.x;
  int l = tid & 63;
  int w = tid >> 6;
  int wm = w >> 1, wn = w & 1;             // 2 x 2 wave grid, 64x64 out per wave

  f32x4 acc[4][4];
#pragma unroll
  for (int m = 0; m < 4; ++m)
#pragma unroll
    for (int n = 0; n < 4; ++n)
#pragma unroll
      for (int r = 0; r < 4; ++r) acc[m][n][r] = 0.f;

  // stage one 128x32 K-tile of A and B (2 granules of 16B each per thread).
  // LDS dest linear (granule g = row*4+slot); global source slot pre-swizzled.
  auto STAGE = [&](int buf, int kt) {
#pragma unroll
    for (int c = 0; c < 2; ++c) {
      int g = c * 256 + tid;               // 0..511
      int row = g >> 2, sl = g & 3;
      int col = kt * 32 + ((sl ^ ((row >> 1) & 3)) << 3);
      __builtin_amdgcn_global_load_lds((CGV*)(A + (long)row * LDA + col),
                                       (LDSV*)(&ldsA[buf][g * 8]), 16, 0, 0);
      __builtin_amdgcn_global_load_lds((CGV*)(B + (long)row * LDB + col),
                                       (LDSV*)(&ldsB[buf][g * 8]), 16, 0, 0);
    }
  };

  int kq = l >> 4;                         // 0..3 k-chunk selector (16B each)
  int l15 = l & 15;

  STAGE(0, 0);
  __syncthreads();

  for (int t = 0; t < KT; ++t) {
    int cur = t & 1;
    if (t + 1 < KT) STAGE(cur ^ 1, t + 1);

    bf16x8 a[4], b[4];
#pragma unroll
    for (int mm = 0; mm < 4; ++mm) {
      int row = wm * 64 + mm * 16 + l15;
      const char* rp = (const char*)&ldsA[cur][row * 32];
      a[mm] = *(const bf16x8*)(rp + ((kq ^ ((row >> 1) & 3)) << 4));
    }
#pragma unroll
    for (int nn = 0; nn < 4; ++nn) {
      int row = wn * 64 + nn * 16 + l15;
      const char* rp = (const char*)&ldsB[cur][row * 32];
      b[nn] = *(const bf16x8*)(rp + ((kq ^ ((row >> 1) & 3)) << 4));
    }

#pragma unroll
    for (int mm = 0; mm < 4; ++mm)
#pragma unroll
      for (int nn = 0; nn < 4; ++nn)
        acc[mm][nn] = __builtin_amdgcn_mfma_f32_16x16x32_bf16(
            a[mm], b[nn], acc[mm][nn], 0, 0, 0);

    if (t + 1 < KT) __syncthreads();
  }

  // epilogue: col=lane&15, row=(lane>>4)*4+r (verified layout)
#pragma unroll
  for (int m = 0; m < 4; ++m) {
    int gr0 = wm * 64 + m * 16 + (l >> 4) * 4;
#pragma unroll
    for (int r = 0; r < 4; ++r) {
#pragma unroll
      for (int n = 0; n < 4; ++n) {
        float vv = acc[m][n][r];
        if (GELU) vv = 0.5f * vv * (1.f + erff(vv * 0.70710678118654752f));
        Cp[(long)(gr0 + r) * LDC + wn * 64 + n * 16 + l15] = f2bf(vv);
      }
    }
  }
}

// ---------------- combine: out[t] = gg1*eo[f1] + gg2*eo[f2] (f32 out) ----------------
__global__ void __launch_bounds__(128) combine_kernel(const short* __restrict__ eo,
    const int* __restrict__ f1, const int* __restrict__ f2,
    const float* __restrict__ gg1, const float* __restrict__ gg2, float* __restrict__ out) {
  int t = blockIdx.x, tid = threadIdx.x;
  float a = gg1[t], b = gg2[t];
  long s1 = f1[t], s2 = f2[t];
  bf16x8 v1 = *(const bf16x8*)(eo + s1 * DDIM + tid * 8);
  bf16x8 v2 = *(const bf16x8*)(eo + s2 * DDIM + tid * 8);
  f32x4 o0, o1;
#pragma unroll
  for (int j = 0; j < 4; ++j) {
    o0[j] = a * bf2f(v1[j])     + b * bf2f(v2[j]);
    o1[j] = a * bf2f(v1[j + 4]) + b * bf2f(v2[j + 4]);
  }
  float* dst = out + (size_t)t * DDIM + tid * 8;
  *(f32x4*)dst = o0;
  *(f32x4*)(dst + 4) = o1;
}

extern "C" void kernel_launch(void* const* d_in, const int* in_sizes, int n_in,
                              void* d_out, int out_size, void* d_ws, size_t ws_size,
                              hipStream_t stream) {
  const float* x      = (const float*)d_in[0];
  const float* wg     = (const float*)d_in[1];
  const float* w_gate = (const float*)d_in[2];
  const float* w_down = (const float*)d_in[3];
  float* out = (float*)d_out;

  char* ws = (char*)d_ws;
  size_t off = 0;
  auto alloc = [&](size_t bytes) -> void* {
    void* p = ws + off;
    off += (bytes + 255) & ~(size_t)255;
    return p;
  };
  short* wbg  = (short*)alloc((size_t)EE * FF * DDIM * 2);   // [E][F][D] bf16
  short* wbd  = (short*)alloc((size_t)EE * DDIM * FF * 2);   // [E][D][F] bf16
  short* disp = (short*)alloc((size_t)NSLOT * DDIM * 2);
  short* eo   = (short*)alloc((size_t)NSLOT * DDIM * 2);
  int*   idx1 = (int*)alloc(TT * 4);
  int*   idx2 = (int*)alloc(TT * 4);
  int*   f1   = (int*)alloc(TT * 4);
  int*   f2   = (int*)alloc(TT * 4);
  float* g1s  = (float*)alloc(TT * 4);
  float* g2s  = (float*)alloc(TT * 4);
  float* gg1  = (float*)alloc(TT * 4);
  float* gg2  = (float*)alloc(TT * 4);
  int*   slot_token = (int*)alloc(NSLOT * 4);
  size_t h_full = (size_t)NSLOT * FF * 2;
  bool full = (off + h_full) <= ws_size;
  short* h = (short*)(ws + off);

  // weights -> bf16, transposed to [N][K]
  tconv_kernel<<<dim3(FF / 32, DDIM / 64, EE), 256, 0, stream>>>(w_gate, wbg, DDIM, FF);
  tconv_kernel<<<dim3(DDIM / 32, FF / 64, EE), 256, 0, stream>>>(w_down, wbd, FF, DDIM);

  gate_kernel<<<TT / 4, 256, 0, stream>>>(x, wg, idx1, idx2, g1s, g2s);
  scan_kernel<<<1, 1024, 0, stream>>>(idx1, idx2, g1s, g2s, f1, f2, gg1, gg2, slot_token);
  dispatch_kernel<<<NSLOT, 128, 0, stream>>>(x, slot_token, disp);

  if (full) {
    gemm128<DDIM, DDIM, DDIM, FF, true><<<(FF / 128) * (CCAP / 128) * EE, 256, 0, stream>>>(
        disp, wbg, h, (long)CCAP * DDIM, (long)FF * DDIM, (long)CCAP * FF, FF / 128, CCAP / 128);
    gemm128<FF, FF, FF, DDIM, false><<<(DDIM / 128) * (CCAP / 128) * EE, 256, 0, stream>>>(
        h, wbd, eo, (long)CCAP * FF, (long)DDIM * FF, (long)CCAP * DDIM, DDIM / 128, CCAP / 128);
  } else {
    for (int e = 0; e < EE; ++e) {
      gemm128<DDIM, DDIM, DDIM, FF, true><<<(FF / 128) * (CCAP / 128), 256, 0, stream>>>(
          disp + (long)e * CCAP * DDIM, wbg + (long)e * FF * DDIM, h, 0, 0, 0, FF / 128, CCAP / 128);
      gemm128<FF, FF, FF, DDIM, false><<<(DDIM / 128) * (CCAP / 128), 256, 0, stream>>>(
          h, wbd + (long)e * DDIM * FF, eo + (long)e * CCAP * DDIM, 0, 0, 0, DDIM / 128, CCAP / 128);
    }
  }

  combine_kernel<<<TT, 128, 0, stream>>>(eo, f1, f2, gg1, gg2, out);
}